// Round 1
// baseline (1264.814 us; speedup 1.0000x reference)
//
#include <hip/hip_runtime.h>
#include <hip/hip_bf16.h>

#define N_NODES 100000
#define N_EDGES 1600000
#define HEADS 8
#define D_K 16
#define ALPHA 0.2f

// Order-preserving float <-> uint mapping for atomicMax on floats.
// All real floats map to ord >= 0x007FFFFF > 0, so a 0-init is "-inf".
__device__ __forceinline__ unsigned ford(float f) {
    unsigned u = __float_as_uint(f);
    return (u & 0x80000000u) ? ~u : (u | 0x80000000u);
}
__device__ __forceinline__ float fdec(unsigned u) {
    u = (u & 0x80000000u) ? (u & 0x7FFFFFFFu) : ~u;
    return __uint_as_float(u);
}

__device__ __forceinline__ float lrelu(float s) {
    return s >= 0.0f ? s : ALPHA * s;
}

// Kernel 1: per-node projections p1[n*8+h] = a1 . x[n, h*16:+16], p2 likewise.
__global__ void proj_kernel(const float* __restrict__ x, const float* __restrict__ a,
                            float* __restrict__ p1, float* __restrict__ p2) {
    int t = blockIdx.x * blockDim.x + threadIdx.x;
    if (t >= N_NODES * HEADS) return;
    int hd = t & 7;
    int n  = t >> 3;
    const float4* xp  = (const float4*)(x + (size_t)n * 128 + hd * 16);
    const float4* a1p = (const float4*)(a);
    const float4* a2p = (const float4*)(a + 16);
    float s1 = 0.f, s2 = 0.f;
#pragma unroll
    for (int i = 0; i < 4; ++i) {
        float4 xv = xp[i];
        float4 v1 = a1p[i];
        float4 v2 = a2p[i];
        s1 += xv.x * v1.x + xv.y * v1.y + xv.z * v1.z + xv.w * v1.w;
        s2 += xv.x * v2.x + xv.y * v2.y + xv.z * v2.z + xv.w * v2.w;
    }
    p1[t] = s1;
    p2[t] = s2;
}

__device__ __forceinline__ void edge_scores(const float* __restrict__ p1,
                                            const float* __restrict__ p2,
                                            int src, int dst, float sv[8]) {
    float4 s1a = *(const float4*)(p1 + (size_t)src * 8);
    float4 s1b = *(const float4*)(p1 + (size_t)src * 8 + 4);
    float4 s2a = *(const float4*)(p2 + (size_t)dst * 8);
    float4 s2b = *(const float4*)(p2 + (size_t)dst * 8 + 4);
    sv[0] = s1a.x + s2a.x; sv[1] = s1a.y + s2a.y;
    sv[2] = s1a.z + s2a.z; sv[3] = s1a.w + s2a.w;
    sv[4] = s1b.x + s2b.x; sv[5] = s1b.y + s2b.y;
    sv[6] = s1b.z + s2b.z; sv[7] = s1b.w + s2b.w;
}

// Kernel 2: per-edge leaky-relu scores -> atomic segment max per (dst, head).
__global__ void segmax_kernel(const int* __restrict__ edge,
                              const float* __restrict__ p1,
                              const float* __restrict__ p2,
                              unsigned* __restrict__ segmax) {
    int e = blockIdx.x * blockDim.x + threadIdx.x;
    if (e >= N_EDGES) return;
    int src = edge[e];
    int dst = edge[N_EDGES + e];
    float sv[8];
    edge_scores(p1, p2, src, dst, sv);
    unsigned* base = segmax + (size_t)dst * 8;
#pragma unroll
    for (int h = 0; h < 8; ++h) {
        atomicMax(&base[h], ford(lrelu(sv[h])));
    }
}

// Kernel 3: ex = exp(e - segmax[dst]) -> atomic segment sum per (dst, head).
__global__ void segsum_kernel(const int* __restrict__ edge,
                              const float* __restrict__ p1,
                              const float* __restrict__ p2,
                              const unsigned* __restrict__ segmax,
                              float* __restrict__ denom) {
    int e = blockIdx.x * blockDim.x + threadIdx.x;
    if (e >= N_EDGES) return;
    int src = edge[e];
    int dst = edge[N_EDGES + e];
    float sv[8];
    edge_scores(p1, p2, src, dst, sv);
    const unsigned* mb = segmax + (size_t)dst * 8;
    float* db = denom + (size_t)dst * 8;
#pragma unroll
    for (int h = 0; h < 8; ++h) {
        float ev = lrelu(sv[h]);
        float m  = fdec(mb[h]);
        atomicAdd(&db[h], __expf(ev - m));
    }
}

// Kernel 4: out[e,h] = exp(e - m) / (denom + 1e-16), coalesced float4 stores.
__global__ void norm_kernel(const int* __restrict__ edge,
                            const float* __restrict__ p1,
                            const float* __restrict__ p2,
                            const unsigned* __restrict__ segmax,
                            const float* __restrict__ denom,
                            float* __restrict__ out) {
    int e = blockIdx.x * blockDim.x + threadIdx.x;
    if (e >= N_EDGES) return;
    int src = edge[e];
    int dst = edge[N_EDGES + e];
    float sv[8];
    edge_scores(p1, p2, src, dst, sv);
    const unsigned* mb = segmax + (size_t)dst * 8;
    const float* db = denom + (size_t)dst * 8;
    float ov[8];
#pragma unroll
    for (int h = 0; h < 8; ++h) {
        float ev = lrelu(sv[h]);
        float m  = fdec(mb[h]);
        float ex = __expf(ev - m);
        ov[h] = ex / (db[h] + 1e-16f);
    }
    float4* op = (float4*)(out + (size_t)e * 8);
    op[0] = make_float4(ov[0], ov[1], ov[2], ov[3]);
    op[1] = make_float4(ov[4], ov[5], ov[6], ov[7]);
}

extern "C" void kernel_launch(void* const* d_in, const int* in_sizes, int n_in,
                              void* d_out, int out_size, void* d_ws, size_t ws_size,
                              hipStream_t stream) {
    const float* x    = (const float*)d_in[0];
    const float* a    = (const float*)d_in[1];
    const int*   edge = (const int*)d_in[2];
    float* out = (float*)d_out;

    // Workspace layout (floats/uints, 800k elems each = 3.2 MB):
    float*    p1     = (float*)d_ws;
    float*    p2     = p1 + (size_t)N_NODES * HEADS;
    unsigned* segmax = (unsigned*)(p2 + (size_t)N_NODES * HEADS);
    float*    denom  = (float*)(segmax + (size_t)N_NODES * HEADS);

    // Zero segmax (ordered-uint "-inf") and denom each call (deterministic).
    hipMemsetAsync(segmax, 0, (size_t)N_NODES * HEADS * sizeof(unsigned) * 2, stream);

    const int TPB = 256;
    int gp = (N_NODES * HEADS + TPB - 1) / TPB;
    int ge = (N_EDGES + TPB - 1) / TPB;

    proj_kernel<<<gp, TPB, 0, stream>>>(x, a, p1, p2);
    segmax_kernel<<<ge, TPB, 0, stream>>>(edge, p1, p2, segmax);
    segsum_kernel<<<ge, TPB, 0, stream>>>(edge, p1, p2, segmax, denom);
    norm_kernel<<<ge, TPB, 0, stream>>>(edge, p1, p2, segmax, denom, out);
}

// Round 2
// 173.923 us; speedup vs baseline: 7.2723x; 7.2723x over previous
//
#include <hip/hip_runtime.h>
#include <hip/hip_bf16.h>

#define N_NODES 100000
#define N_EDGES 1600000
#define HEADS 8
#define ALPHA 0.2f

#define BSHIFT 7
#define BSIZE 128               // dst nodes per bucket
#define NBUCK 782               // ceil(100000 / 128)
#define EPB 4096                // edges per hist/scatter block
#define NEB 391                 // ceil(1600000 / 4096)

__device__ __forceinline__ float lrelu(float s) {
    return s >= 0.0f ? s : ALPHA * s;
}

// Kernel 1: per-node projections p1[n*8+h] = a1 . x[n, h*16:+16], p2 likewise.
__global__ void proj_kernel(const float* __restrict__ x, const float* __restrict__ a,
                            float* __restrict__ p1, float* __restrict__ p2) {
    int t = blockIdx.x * blockDim.x + threadIdx.x;
    if (t >= N_NODES * HEADS) return;
    int hd = t & 7;
    int n  = t >> 3;
    const float4* xp  = (const float4*)(x + (size_t)n * 128 + hd * 16);
    const float4* a1p = (const float4*)(a);
    const float4* a2p = (const float4*)(a + 16);
    float s1 = 0.f, s2 = 0.f;
#pragma unroll
    for (int i = 0; i < 4; ++i) {
        float4 xv = xp[i];
        float4 v1 = a1p[i];
        float4 v2 = a2p[i];
        s1 += xv.x * v1.x + xv.y * v1.y + xv.z * v1.z + xv.w * v1.w;
        s2 += xv.x * v2.x + xv.y * v2.y + xv.z * v2.z + xv.w * v2.w;
    }
    p1[t] = s1;
    p2[t] = s2;
}

// Kernel 2: per-block LDS histogram of dst buckets -> global bucket counts.
__global__ __launch_bounds__(1024) void hist_kernel(const int* __restrict__ edge,
                                                    unsigned* __restrict__ gcount) {
    __shared__ unsigned lh[NBUCK];
    int t = threadIdx.x;
    for (int i = t; i < NBUCK; i += 1024) lh[i] = 0;
    __syncthreads();
    int base = blockIdx.x * EPB;
#pragma unroll
    for (int k = 0; k < EPB / 1024; ++k) {
        int e = base + k * 1024 + t;
        if (e < N_EDGES) atomicAdd(&lh[(unsigned)edge[N_EDGES + e] >> BSHIFT], 1u);
    }
    __syncthreads();
    for (int i = t; i < NBUCK; i += 1024)
        if (lh[i]) atomicAdd(&gcount[i], lh[i]);
}

// Kernel 3: exclusive scan of 782 bucket counts (single block).
__global__ __launch_bounds__(1024) void scan_kernel(const unsigned* __restrict__ gcount,
                                                    unsigned* __restrict__ goff,
                                                    unsigned* __restrict__ gcur) {
    __shared__ unsigned s[1024];
    int t = threadIdx.x;
    unsigned v = (t < NBUCK) ? gcount[t] : 0u;
    s[t] = v;
    __syncthreads();
    for (int d = 1; d < 1024; d <<= 1) {
        unsigned add = (t >= d) ? s[t - d] : 0u;
        __syncthreads();
        s[t] += add;
        __syncthreads();
    }
    if (t < NBUCK) {
        unsigned excl = s[t] - v;
        goff[t] = excl;
        gcur[t] = excl;
    }
    if (t == 0) goff[NBUCK] = N_EDGES;
}

// Kernel 4: scatter edges into bucket-sorted order. One global int atomic per
// (block, nonempty bucket); per-edge cursor work stays in LDS.
__global__ __launch_bounds__(1024) void scatter_kernel(const int* __restrict__ edge,
                                                       unsigned* __restrict__ gcur,
                                                       unsigned long long* __restrict__ sorted) {
    __shared__ int lsrc[EPB];
    __shared__ int ldst[EPB];
    __shared__ unsigned lh[NBUCK];
    __shared__ unsigned lbase[NBUCK];
    int t = threadIdx.x;
    int base = blockIdx.x * EPB;
    for (int i = t; i < NBUCK; i += 1024) lh[i] = 0;
    __syncthreads();
#pragma unroll
    for (int k = 0; k < EPB / 1024; ++k) {
        int i = k * 1024 + t, e = base + i;
        if (e < N_EDGES) {
            lsrc[i] = edge[e];
            int d = edge[N_EDGES + e];
            ldst[i] = d;
            atomicAdd(&lh[(unsigned)d >> BSHIFT], 1u);
        }
    }
    __syncthreads();
    for (int i = t; i < NBUCK; i += 1024) {
        unsigned c = lh[i];
        lbase[i] = c ? atomicAdd(&gcur[i], c) : 0u;
        lh[i] = 0;   // reuse as local cursor
    }
    __syncthreads();
#pragma unroll
    for (int k = 0; k < EPB / 1024; ++k) {
        int i = k * 1024 + t, e = base + i;
        if (e < N_EDGES) {
            int d = ldst[i];
            unsigned b = (unsigned)d >> BSHIFT;
            unsigned pos = lbase[b] + atomicAdd(&lh[b], 1u);
            sorted[pos] = ((unsigned long long)(unsigned)e << 32)
                        | ((unsigned)lsrc[i] << BSHIFT)
                        | (unsigned)(d & (BSIZE - 1));
        }
    }
}

// Kernel 5: one block per bucket. Accumulate exp(lrelu(e)) into an LDS tile
// (block exclusively owns its 128 dst nodes -> no global atomics), then write
// the final normalized output directly.
__global__ __launch_bounds__(512) void accum_kernel(const unsigned long long* __restrict__ sorted,
                                                    const unsigned* __restrict__ goff,
                                                    const float* __restrict__ p1,
                                                    const float* __restrict__ p2,
                                                    float* __restrict__ out) {
    __shared__ float acc[BSIZE * HEADS];   // 4 KB denominators
    __shared__ float p2t[BSIZE * HEADS];   // 4 KB p2 tile for this bucket
    int t = threadIdx.x;
    int b = blockIdx.x;
    for (int i = t; i < BSIZE * HEADS; i += 512) {
        acc[i] = 0.f;
        int gi = b * BSIZE * HEADS + i;     // == node*8 + h, contiguous
        p2t[i] = (gi < N_NODES * HEADS) ? p2[gi] : 0.f;
    }
    __syncthreads();
    unsigned s0 = goff[b], s1 = goff[b + 1];
    int h = t & 7;
    for (unsigned idx = s0 + (t >> 3); idx < s1; idx += 64) {
        unsigned long long rec = sorted[idx];
        unsigned lo = (unsigned)rec;
        int src = lo >> BSHIFT;
        int dl  = lo & (BSIZE - 1);
        float e  = p1[(size_t)src * 8 + h] + p2t[dl * 8 + h];
        float ex = __expf(lrelu(e));
        atomicAdd(&acc[dl * 8 + h], ex);   // LDS float atomic (ds_add)
    }
    __syncthreads();
    for (unsigned idx = s0 + (t >> 3); idx < s1; idx += 64) {
        unsigned long long rec = sorted[idx];
        unsigned eid = (unsigned)(rec >> 32);
        unsigned lo  = (unsigned)rec;
        int src = lo >> BSHIFT;
        int dl  = lo & (BSIZE - 1);
        float e  = p1[(size_t)src * 8 + h] + p2t[dl * 8 + h];
        float ex = __expf(lrelu(e));
        out[(size_t)eid * 8 + h] = ex / (acc[dl * 8 + h] + 1e-16f);
    }
}

extern "C" void kernel_launch(void* const* d_in, const int* in_sizes, int n_in,
                              void* d_out, int out_size, void* d_ws, size_t ws_size,
                              hipStream_t stream) {
    const float* x    = (const float*)d_in[0];
    const float* a    = (const float*)d_in[1];
    const int*   edge = (const int*)d_in[2];
    float* out = (float*)d_out;

    // Workspace layout (~19.2 MB):
    unsigned long long* sorted = (unsigned long long*)d_ws;          // 12.8 MB
    float*    p1     = (float*)(sorted + N_EDGES);                   // 3.2 MB
    float*    p2     = p1 + (size_t)N_NODES * HEADS;                 // 3.2 MB
    unsigned* gcount = (unsigned*)(p2 + (size_t)N_NODES * HEADS);    // 782
    unsigned* goff   = gcount + NBUCK;                               // 783
    unsigned* gcur   = goff + NBUCK + 1;                             // 782

    hipMemsetAsync(gcount, 0, NBUCK * sizeof(unsigned), stream);

    const int TPB = 256;
    int gp = (N_NODES * HEADS + TPB - 1) / TPB;

    proj_kernel<<<gp, TPB, 0, stream>>>(x, a, p1, p2);
    hist_kernel<<<NEB, 1024, 0, stream>>>(edge, gcount);
    scan_kernel<<<1, 1024, 0, stream>>>(gcount, goff, gcur);
    scatter_kernel<<<NEB, 1024, 0, stream>>>(edge, gcur, sorted);
    accum_kernel<<<NBUCK, 512, 0, stream>>>(sorted, goff, p1, p2, out);
}

// Round 3
// 153.608 us; speedup vs baseline: 8.2340x; 1.1323x over previous
//
#include <hip/hip_runtime.h>
#include <hip/hip_bf16.h>

#define N_NODES 100000
#define N_EDGES 1600000
#define HEADS 8
#define ALPHA 0.2f

#define BSHIFT 7
#define BSIZE 128               // dst nodes per bucket
#define NBUCK 782               // ceil(100000 / 128)
#define EPB 4096                // edges per hist/scatter block
#define NEB 391                 // ceil(1600000 / 4096)
#define MAXK 5                  // register-cached edges per thread (2560/bucket)

__device__ __forceinline__ float lrelu(float s) {
    return s >= 0.0f ? s : ALPHA * s;
}

// Kernel 1: per-node projections p1[n*8+h] = a1 . x[n, h*16:+16], p2 likewise.
__global__ void proj_kernel(const float* __restrict__ x, const float* __restrict__ a,
                            float* __restrict__ p1, float* __restrict__ p2) {
    int t = blockIdx.x * blockDim.x + threadIdx.x;
    if (t >= N_NODES * HEADS) return;
    int hd = t & 7;
    int n  = t >> 3;
    const float4* xp  = (const float4*)(x + (size_t)n * 128 + hd * 16);
    const float4* a1p = (const float4*)(a);
    const float4* a2p = (const float4*)(a + 16);
    float s1 = 0.f, s2 = 0.f;
#pragma unroll
    for (int i = 0; i < 4; ++i) {
        float4 xv = xp[i];
        float4 v1 = a1p[i];
        float4 v2 = a2p[i];
        s1 += xv.x * v1.x + xv.y * v1.y + xv.z * v1.z + xv.w * v1.w;
        s2 += xv.x * v2.x + xv.y * v2.y + xv.z * v2.z + xv.w * v2.w;
    }
    p1[t] = s1;
    p2[t] = s2;
}

// Kernel 2: per-block LDS histogram of dst buckets -> global bucket counts.
__global__ __launch_bounds__(1024) void hist_kernel(const int* __restrict__ edge,
                                                    unsigned* __restrict__ gcount) {
    __shared__ unsigned lh[NBUCK];
    int t = threadIdx.x;
    for (int i = t; i < NBUCK; i += 1024) lh[i] = 0;
    __syncthreads();
    int base = blockIdx.x * EPB;
#pragma unroll
    for (int k = 0; k < EPB / 1024; ++k) {
        int e = base + k * 1024 + t;
        if (e < N_EDGES) atomicAdd(&lh[(unsigned)edge[N_EDGES + e] >> BSHIFT], 1u);
    }
    __syncthreads();
    for (int i = t; i < NBUCK; i += 1024)
        if (lh[i]) atomicAdd(&gcount[i], lh[i]);
}

// Kernel 3: exclusive scan of 782 bucket counts (single block).
__global__ __launch_bounds__(1024) void scan_kernel(const unsigned* __restrict__ gcount,
                                                    unsigned* __restrict__ goff,
                                                    unsigned* __restrict__ gcur) {
    __shared__ unsigned s[1024];
    int t = threadIdx.x;
    unsigned v = (t < NBUCK) ? gcount[t] : 0u;
    s[t] = v;
    __syncthreads();
    for (int d = 1; d < 1024; d <<= 1) {
        unsigned add = (t >= d) ? s[t - d] : 0u;
        __syncthreads();
        s[t] += add;
        __syncthreads();
    }
    if (t < NBUCK) {
        unsigned excl = s[t] - v;
        goff[t] = excl;
        gcur[t] = excl;
    }
    if (t == 0) goff[NBUCK] = N_EDGES;
}

// Kernel 4: scatter edges into bucket-sorted order. One global int atomic per
// (block, nonempty bucket); per-edge cursor work stays in LDS.
__global__ __launch_bounds__(1024) void scatter_kernel(const int* __restrict__ edge,
                                                       unsigned* __restrict__ gcur,
                                                       unsigned long long* __restrict__ sorted) {
    __shared__ int lsrc[EPB];
    __shared__ int ldst[EPB];
    __shared__ unsigned lh[NBUCK];
    __shared__ unsigned lbase[NBUCK];
    int t = threadIdx.x;
    int base = blockIdx.x * EPB;
    for (int i = t; i < NBUCK; i += 1024) lh[i] = 0;
    __syncthreads();
#pragma unroll
    for (int k = 0; k < EPB / 1024; ++k) {
        int i = k * 1024 + t, e = base + i;
        if (e < N_EDGES) {
            lsrc[i] = edge[e];
            int d = edge[N_EDGES + e];
            ldst[i] = d;
            atomicAdd(&lh[(unsigned)d >> BSHIFT], 1u);
        }
    }
    __syncthreads();
    for (int i = t; i < NBUCK; i += 1024) {
        unsigned c = lh[i];
        lbase[i] = c ? atomicAdd(&gcur[i], c) : 0u;
        lh[i] = 0;   // reuse as local cursor
    }
    __syncthreads();
#pragma unroll
    for (int k = 0; k < EPB / 1024; ++k) {
        int i = k * 1024 + t, e = base + i;
        if (e < N_EDGES) {
            int d = ldst[i];
            unsigned b = (unsigned)d >> BSHIFT;
            unsigned pos = lbase[b] + atomicAdd(&lh[b], 1u);
            sorted[pos] = ((unsigned long long)(unsigned)e << 32)
                        | ((unsigned)lsrc[i] << BSHIFT)
                        | (unsigned)(d & (BSIZE - 1));
        }
    }
}

// Kernel 5: one block per bucket. Pass 1: accumulate exp into LDS tile
// ([h][dl] layout -> bank = dl%32, ~2-way), caching each thread's exp values
// and edge records in REGISTERS. Invert denominators once. Pass 2: multiply
// cached exp by cached reciprocal, store out. No global atomics anywhere.
__global__ __launch_bounds__(512) void accum_kernel(const unsigned long long* __restrict__ sorted,
                                                    const unsigned* __restrict__ goff,
                                                    const float* __restrict__ p1,
                                                    const float* __restrict__ p2,
                                                    float* __restrict__ out) {
    __shared__ float acc[HEADS * BSIZE];   // [h][dl], 4 KB
    __shared__ float p2t[HEADS * BSIZE];   // [h][dl], 4 KB
    int t = threadIdx.x;
    int b = blockIdx.x;
    for (int i = t; i < BSIZE * HEADS; i += 512) {
        acc[i] = 0.f;
        int gi = b * BSIZE * HEADS + i;     // global p2 index = node*8 + h
        int dl = i >> 3, h = i & 7;
        p2t[h * BSIZE + dl] = (gi < N_NODES * HEADS) ? p2[gi] : 0.f;
    }
    __syncthreads();
    unsigned s0 = goff[b], s1 = goff[b + 1];

    unsigned long long rec[MAXK];
    float ex[MAXK][8];
    bool valid[MAXK];
#pragma unroll
    for (int k = 0; k < MAXK; ++k) {
        unsigned idx = s0 + t + k * 512;
        valid[k] = (idx < s1);
        if (valid[k]) rec[k] = sorted[idx];
    }
#pragma unroll
    for (int k = 0; k < MAXK; ++k) {
        if (valid[k]) {
            unsigned lo = (unsigned)rec[k];
            int src = lo >> BSHIFT;
            int dl  = lo & (BSIZE - 1);
            const float4* pp = (const float4*)(p1 + (size_t)src * 8);
            float4 pa = pp[0];
            float4 pb = pp[1];
            float sv[8] = {pa.x, pa.y, pa.z, pa.w, pb.x, pb.y, pb.z, pb.w};
#pragma unroll
            for (int h = 0; h < 8; ++h)
                ex[k][h] = __expf(lrelu(sv[h] + p2t[h * BSIZE + dl]));
#pragma unroll
            for (int h = 0; h < 8; ++h)
                atomicAdd(&acc[h * BSIZE + dl], ex[k][h]);   // ds_add, no rtn
        }
    }
    // Fallback for pathologically large buckets (>2560 edges): recompute path.
    for (unsigned idx = s0 + t + MAXK * 512; idx < s1; idx += 512) {
        unsigned lo = (unsigned)sorted[idx];
        int src = lo >> BSHIFT;
        int dl  = lo & (BSIZE - 1);
        const float4* pp = (const float4*)(p1 + (size_t)src * 8);
        float4 pa = pp[0];
        float4 pb = pp[1];
        float sv[8] = {pa.x, pa.y, pa.z, pa.w, pb.x, pb.y, pb.z, pb.w};
#pragma unroll
        for (int h = 0; h < 8; ++h)
            atomicAdd(&acc[h * BSIZE + dl], __expf(lrelu(sv[h] + p2t[h * BSIZE + dl])));
    }
    __syncthreads();
    for (int i = t; i < BSIZE * HEADS; i += 512)
        acc[i] = 1.0f / (acc[i] + 1e-16f);
    __syncthreads();
#pragma unroll
    for (int k = 0; k < MAXK; ++k) {
        if (valid[k]) {
            unsigned eid = (unsigned)(rec[k] >> 32);
            int dl = (unsigned)rec[k] & (BSIZE - 1);
            float ov[8];
#pragma unroll
            for (int h = 0; h < 8; ++h)
                ov[h] = ex[k][h] * acc[h * BSIZE + dl];
            float4* op = (float4*)(out + (size_t)eid * 8);
            op[0] = make_float4(ov[0], ov[1], ov[2], ov[3]);
            op[1] = make_float4(ov[4], ov[5], ov[6], ov[7]);
        }
    }
    for (unsigned idx = s0 + t + MAXK * 512; idx < s1; idx += 512) {
        unsigned long long r = sorted[idx];
        unsigned eid = (unsigned)(r >> 32);
        unsigned lo  = (unsigned)r;
        int src = lo >> BSHIFT;
        int dl  = lo & (BSIZE - 1);
        const float4* pp = (const float4*)(p1 + (size_t)src * 8);
        float4 pa = pp[0];
        float4 pb = pp[1];
        float sv[8] = {pa.x, pa.y, pa.z, pa.w, pb.x, pb.y, pb.z, pb.w};
        float ov[8];
#pragma unroll
        for (int h = 0; h < 8; ++h)
            ov[h] = __expf(lrelu(sv[h] + p2t[h * BSIZE + dl])) * acc[h * BSIZE + dl];
        float4* op = (float4*)(out + (size_t)eid * 8);
        op[0] = make_float4(ov[0], ov[1], ov[2], ov[3]);
        op[1] = make_float4(ov[4], ov[5], ov[6], ov[7]);
    }
}

extern "C" void kernel_launch(void* const* d_in, const int* in_sizes, int n_in,
                              void* d_out, int out_size, void* d_ws, size_t ws_size,
                              hipStream_t stream) {
    const float* x    = (const float*)d_in[0];
    const float* a    = (const float*)d_in[1];
    const int*   edge = (const int*)d_in[2];
    float* out = (float*)d_out;

    // Workspace layout (~19.2 MB):
    unsigned long long* sorted = (unsigned long long*)d_ws;          // 12.8 MB
    float*    p1     = (float*)(sorted + N_EDGES);                   // 3.2 MB
    float*    p2     = p1 + (size_t)N_NODES * HEADS;                 // 3.2 MB
    unsigned* gcount = (unsigned*)(p2 + (size_t)N_NODES * HEADS);    // 782
    unsigned* goff   = gcount + NBUCK;                               // 783
    unsigned* gcur   = goff + NBUCK + 1;                             // 782

    hipMemsetAsync(gcount, 0, NBUCK * sizeof(unsigned), stream);

    const int TPB = 256;
    int gp = (N_NODES * HEADS + TPB - 1) / TPB;

    proj_kernel<<<gp, TPB, 0, stream>>>(x, a, p1, p2);
    hist_kernel<<<NEB, 1024, 0, stream>>>(edge, gcount);
    scan_kernel<<<1, 1024, 0, stream>>>(gcount, goff, gcur);
    scatter_kernel<<<NEB, 1024, 0, stream>>>(edge, gcur, sorted);
    accum_kernel<<<NBUCK, 512, 0, stream>>>(sorted, goff, p1, p2, out);
}